// Round 1
// baseline (195.688 us; speedup 1.0000x reference)
//
#include <hip/hip_runtime.h>
#include <hip/hip_bf16.h>
#include <math.h>

// Problem constants
#define B_ROWS 8192
#define N_PTS  16384
#define D_DIM  256

// GEMM tiling
#define BM 128
#define BN 128
#define BK 32
#define KSTEPS (D_DIM / BK)     // 8
#define NSPLIT 16
#define CHUNK  (N_PTS / NSPLIT) // 1024
#define NTILES (CHUNK / BN)     // 8

// Folded constants
#define SCALE_F 144.26950408889634f   // 100 * log2(e)   (logits scaled to log2 domain)
#define LN2_F   0.6931471805599453f
#define LOG2E_F 1.4426950408889634f
#define GN_F    354.2135193f          // -(256/2) * ln(2*pi*0.01)

typedef __attribute__((ext_vector_type(8))) __bf16 bf16x8;
typedef __attribute__((ext_vector_type(4))) float  f32x4;

__device__ __forceinline__ float fexp2(float x) {
#if __has_builtin(__builtin_amdgcn_exp2f)
    return __builtin_amdgcn_exp2f(x);   // flush-to-zero below 2^-126 is exactly what LSE wants
#else
    return exp2f(x);
#endif
}

__device__ __forceinline__ void async_load16(const void* g, void* l) {
    __builtin_amdgcn_global_load_lds(
        (const __attribute__((address_space(1))) void*)g,
        (__attribute__((address_space(3))) void*)l,
        16, 0, 0);
}

// ---- prep: x -> bf16, row const rc[b] = GN - 50*||x_b||^2 ----
// one wave per row, float4 loads, ushort4 (8B) bf16 stores
__global__ void prep_x_kernel(const float* __restrict__ x, __bf16* __restrict__ xb,
                              float* __restrict__ rc)
{
    const int lane = threadIdx.x & 63;
    const int wv   = threadIdx.x >> 6;
    const int row  = blockIdx.x * 4 + wv;
    const float4 v = *((const float4*)(x + (size_t)row * D_DIM) + lane);
    union { __bf16 h[4]; ushort4 u; } cv;
    cv.h[0] = (__bf16)v.x; cv.h[1] = (__bf16)v.y;
    cv.h[2] = (__bf16)v.z; cv.h[3] = (__bf16)v.w;
    *((ushort4*)((unsigned short*)xb + (size_t)row * D_DIM) + lane) = cv.u;
    float sq = fmaf(v.x, v.x, fmaf(v.y, v.y, fmaf(v.z, v.z, v.w * v.w)));
    #pragma unroll
    for (int off = 32; off; off >>= 1) sq += __shfl_down(sq, off);
    if (lane == 0) rc[row] = GN_F - 50.0f * sq;
}

// ---- prep: X -> bf16, col const c2[n] = (W[n] - 50*||X_n||^2)*log2e ----
__global__ void prep_X_kernel(const float* __restrict__ X, const float* __restrict__ W,
                              __bf16* __restrict__ Xb, float* __restrict__ c2)
{
    const int lane = threadIdx.x & 63;
    const int wv   = threadIdx.x >> 6;
    const int row  = blockIdx.x * 4 + wv;
    const float4 v = *((const float4*)(X + (size_t)row * D_DIM) + lane);
    union { __bf16 h[4]; ushort4 u; } cv;
    cv.h[0] = (__bf16)v.x; cv.h[1] = (__bf16)v.y;
    cv.h[2] = (__bf16)v.z; cv.h[3] = (__bf16)v.w;
    *((ushort4*)((unsigned short*)Xb + (size_t)row * D_DIM) + lane) = cv.u;
    float sq = fmaf(v.x, v.x, fmaf(v.y, v.y, fmaf(v.z, v.z, v.w * v.w)));
    #pragma unroll
    for (int off = 32; off; off >>= 1) sq += __shfl_down(sq, off);
    if (lane == 0) c2[row] = (W[row] - 50.0f * sq) * LOG2E_F;
}

// ---- prep: lseW = logsumexp(W) (natural log) ----
// float4 loads held in registers across both passes (64 VGPR, single block)
__global__ void prep_w_kernel(const float* __restrict__ W, float* __restrict__ lsew)
{
    const int t = threadIdx.x;   // 256 threads
    float4 v[16];
    float mx = -INFINITY;
    #pragma unroll
    for (int i = 0; i < 16; ++i) {
        v[i] = ((const float4*)W)[i * 256 + t];
        mx = fmaxf(mx, fmaxf(fmaxf(v[i].x, v[i].y), fmaxf(v[i].z, v[i].w)));
    }
    #pragma unroll
    for (int off = 32; off; off >>= 1) mx = fmaxf(mx, __shfl_xor(mx, off));
    __shared__ float sm[4];
    __shared__ float ss[4];
    if ((t & 63) == 0) sm[t >> 6] = mx;
    __syncthreads();
    const float M = fmaxf(fmaxf(sm[0], sm[1]), fmaxf(sm[2], sm[3]));
    float acc = 0.f;
    #pragma unroll
    for (int i = 0; i < 16; ++i)
        acc += __expf(v[i].x - M) + __expf(v[i].y - M) + __expf(v[i].z - M) + __expf(v[i].w - M);
    #pragma unroll
    for (int off = 32; off; off >>= 1) acc += __shfl_xor(acc, off);
    if ((t & 63) == 0) ss[t >> 6] = acc;
    __syncthreads();
    if (t == 0) lsew[0] = M + __logf(ss[0] + ss[1] + ss[2] + ss[3]);
}

// ---- main: fused bf16 MFMA GEMM + online log2-sum-exp over n-chunk ----
// v2: 2-phase double-buffered prefetch (1 barrier / k-step) + XOR granule
// swizzle (linear LDS dest for global_load_lds, pre-swizzled per-lane global
// source, swizzled ds_read address) + NSPLIT=16 for 3 blocks/CU residency.
__global__ __launch_bounds__(256, 2) void kde_gemm(
    const __bf16* __restrict__ xb, const __bf16* __restrict__ Xb,
    const float* __restrict__ c2, float* __restrict__ pm, float* __restrict__ ps)
{
    __shared__ __align__(16) __bf16 As[2][BM * BK];   // 2 x 8 KB
    __shared__ __align__(16) __bf16 Bs[2][BN * BK];   // 2 x 8 KB
    __shared__ float redM[2][BM];
    __shared__ float redS[2][BM];

    const int tid  = threadIdx.x;
    const int lane = tid & 63;
    const int w    = tid >> 6;
    const int wy   = w >> 1;
    const int wx   = w & 1;
    const int l15  = lane & 15;
    const int quad = lane >> 4;
    // swizzled 16B-granule column for frag reads: physical granule (row,q)
    // holds logical column q ^ ((row>>1)&3); (row>>1)&3 == (l15>>1)&3 here.
    const int qx   = quad ^ ((l15 >> 1) & 3);

    const int b0    = blockIdx.x * BM;
    const int nbase = blockIdx.y * CHUNK;

    // per-lane online LSE state: rows = wy*64 + i*16 + quad*4 + r
    float m_[4][4], s_[4][4];
    #pragma unroll
    for (int i = 0; i < 4; ++i)
        #pragma unroll
        for (int r = 0; r < 4; ++r) { m_[i][r] = -INFINITY; s_[i][r] = 0.0f; }

    // staging geometry: granule idx = q*256 + tid; row = idx>>2, kc = idx&3
    // source column pre-swizzled so the LINEAR global_load_lds dest yields the
    // swizzled layout the reads expect (rule #21: both-sides-or-neither).
    const int row0 = tid >> 2;                       // 0..63 (second load: +64)
    const int kcs  = (tid & 3) ^ ((tid >> 3) & 3);   // kc ^ ((row>>1)&3), same for row+64
    const int ldsoff0 = w * 512;                     // elements; wave-uniform
    const int ldsoff1 = 2048 + w * 512;

    const __bf16* aSrc0 = xb + (size_t)(b0 + row0) * D_DIM + kcs * 8;
    const __bf16* aSrc1 = aSrc0 + (size_t)64 * D_DIM;
    const __bf16* bSrc0 = Xb + (size_t)(nbase + row0) * D_DIM + kcs * 8;
    const __bf16* bSrc1 = bSrc0 + (size_t)64 * D_DIM;

    // prologue: stage (nt=0, kt=0) into buffer 0
    async_load16(aSrc0, &As[0][ldsoff0]);
    async_load16(aSrc1, &As[0][ldsoff1]);
    async_load16(bSrc0, &Bs[0][ldsoff0]);
    async_load16(bSrc1, &Bs[0][ldsoff1]);

    for (int nt = 0; nt < NTILES; ++nt) {
        const int n0 = nbase + nt * BN;
        float c2v[4];

        f32x4 acc[4][4];
        #pragma unroll
        for (int i = 0; i < 4; ++i)
            #pragma unroll
            for (int j = 0; j < 4; ++j) {
                f32x4 z = {0.f, 0.f, 0.f, 0.f};
                acc[i][j] = z;
            }

        #pragma unroll
        for (int kt = 0; kt < KSTEPS; ++kt) {
            // barrier: (a) stage for this step (issued last step) drained by the
            // compiler's vmcnt(0) here; (b) all waves done reading the buffer the
            // next stage will overwrite.
            __syncthreads();
            const int cb  = kt & 1;            // compile-time under unroll
            const int nb2 = cb ^ 1;

            if (!(nt == NTILES - 1 && kt == KSTEPS - 1)) {
                const int ntN = (kt == KSTEPS - 1) ? nt + 1 : nt;
                const int ktN = (kt + 1) & (KSTEPS - 1);
                const size_t aoff = (size_t)ktN * BK;
                const size_t boff = (size_t)ntN * BN * D_DIM + (size_t)ktN * BK;
                async_load16(aSrc0 + aoff, &As[nb2][ldsoff0]);
                async_load16(aSrc1 + aoff, &As[nb2][ldsoff1]);
                async_load16(bSrc0 + boff, &Bs[nb2][ldsoff0]);
                async_load16(bSrc1 + boff, &Bs[nb2][ldsoff1]);
            }
            if (kt == KSTEPS - 1) {
                #pragma unroll
                for (int j = 0; j < 4; ++j)
                    c2v[j] = c2[n0 + wx * 64 + j * 16 + l15];
            }

            bf16x8 af[4], bfr[4];
            #pragma unroll
            for (int i = 0; i < 4; ++i)
                af[i] = *(const bf16x8*)&As[cb][(wy * 64 + i * 16 + l15) * BK + qx * 8];
            #pragma unroll
            for (int j = 0; j < 4; ++j)
                bfr[j] = *(const bf16x8*)&Bs[cb][(wx * 64 + j * 16 + l15) * BK + qx * 8];
            #pragma unroll
            for (int i = 0; i < 4; ++i)
                #pragma unroll
                for (int j = 0; j < 4; ++j)
                    acc[i][j] = __builtin_amdgcn_mfma_f32_16x16x32_bf16(af[i], bfr[j], acc[i][j], 0, 0, 0);
        }

        // fused epilogue: online LSE (log2 domain), purely per-lane.
        // Sits before the next tile's barrier -> overlaps the in-flight stage.
        #pragma unroll
        for (int i = 0; i < 4; ++i) {
            #pragma unroll
            for (int r = 0; r < 4; ++r) {
                float v0 = fmaf(SCALE_F, acc[i][0][r], c2v[0]);
                float v1 = fmaf(SCALE_F, acc[i][1][r], c2v[1]);
                float v2 = fmaf(SCALE_F, acc[i][2][r], c2v[2]);
                float v3 = fmaf(SCALE_F, acc[i][3][r], c2v[3]);
                float tm = fmaxf(fmaxf(v0, v1), fmaxf(v2, v3));
                float om = m_[i][r];
                float nm = fmaxf(om, tm);
                float e  = fexp2(v0 - nm) + fexp2(v1 - nm) + fexp2(v2 - nm) + fexp2(v3 - nm);
                s_[i][r] = fmaf(s_[i][r], fexp2(om - nm), e);
                m_[i][r] = nm;
            }
        }
    }

    // reduce (m,s) across the 16 lanes sharing each row, then across wx waves
    #pragma unroll
    for (int i = 0; i < 4; ++i) {
        #pragma unroll
        for (int r = 0; r < 4; ++r) {
            float mm = m_[i][r], ss = s_[i][r];
            #pragma unroll
            for (int off = 1; off < 16; off <<= 1) {
                float om = __shfl_xor(mm, off);
                float os = __shfl_xor(ss, off);
                float nm = fmaxf(mm, om);
                ss = ss * fexp2(mm - nm) + os * fexp2(om - nm);
                mm = nm;
            }
            if (l15 == 0) {
                int row = wy * 64 + i * 16 + quad * 4 + r;
                redM[wx][row] = mm;
                redS[wx][row] = ss;
            }
        }
    }
    __syncthreads();
    if (tid < BM) {
        float m0 = redM[0][tid], m1 = redM[1][tid];
        float s0 = redS[0][tid], s1 = redS[1][tid];
        float M = fmaxf(m0, m1);
        float S = s0 * fexp2(m0 - M) + s1 * fexp2(m1 - M);
        pm[(size_t)(b0 + tid) * NSPLIT + blockIdx.y] = M;
        ps[(size_t)(b0 + tid) * NSPLIT + blockIdx.y] = S;
    }
}

// ---- combine partial (m,s) across N-chunks ----
__global__ void kde_combine(const float* __restrict__ pm, const float* __restrict__ ps,
                            const float* __restrict__ rc, const float* __restrict__ lsew,
                            float* __restrict__ out)
{
    int b = blockIdx.x * blockDim.x + threadIdx.x;
    if (b >= B_ROWS) return;
    float M = -INFINITY;
    #pragma unroll
    for (int c = 0; c < NSPLIT; ++c) M = fmaxf(M, pm[(size_t)b * NSPLIT + c]);
    float S = 0.f;
    #pragma unroll
    for (int c = 0; c < NSPLIT; ++c)
        S += ps[(size_t)b * NSPLIT + c] * fexp2(pm[(size_t)b * NSPLIT + c] - M);
    out[b] = (M + log2f(S)) * LN2_F + rc[b] - lsew[0];
}

extern "C" void kernel_launch(void* const* d_in, const int* in_sizes, int n_in,
                              void* d_out, int out_size, void* d_ws, size_t ws_size,
                              hipStream_t stream)
{
    const float* x = (const float*)d_in[0];
    const float* X = (const float*)d_in[1];
    const float* W = (const float*)d_in[2];
    float* out = (float*)d_out;

    char* ws = (char*)d_ws;
    size_t off = 0;
    __bf16* xb = (__bf16*)(ws + off); off += (size_t)B_ROWS * D_DIM * 2;   // 4 MB
    __bf16* Xb = (__bf16*)(ws + off); off += (size_t)N_PTS  * D_DIM * 2;   // 8 MB
    float* rc   = (float*)(ws + off); off += (size_t)B_ROWS * 4;
    float* c2   = (float*)(ws + off); off += (size_t)N_PTS * 4;
    float* lsew = (float*)(ws + off); off += 256;
    float* pm   = (float*)(ws + off); off += (size_t)B_ROWS * NSPLIT * 4;
    float* ps   = (float*)(ws + off); off += (size_t)B_ROWS * NSPLIT * 4;

    prep_x_kernel<<<B_ROWS / 4, 256, 0, stream>>>(x, xb, rc);
    prep_X_kernel<<<N_PTS / 4, 256, 0, stream>>>(X, W, Xb, c2);
    prep_w_kernel<<<1, 256, 0, stream>>>(W, lsew);
    kde_gemm<<<dim3(B_ROWS / BM, NSPLIT), 256, 0, stream>>>(xb, Xb, c2, pm, ps);
    kde_combine<<<B_ROWS / 256, 256, 0, stream>>>(pm, ps, rc, lsew, out);
}